// Round 6
// baseline (392.834 us; speedup 1.0000x reference)
//
#include <hip/hip_runtime.h>
#include <hip/hip_bf16.h>

#define NN 50000
#define NE 400000
#define AVG_LOG_F 2.1972245773362196f
#define EPSV 1e-5f

typedef __hip_bfloat16 bf16;
typedef __attribute__((ext_vector_type(8))) short short8v;
typedef __attribute__((ext_vector_type(4))) float f32x4;

__device__ __forceinline__ float b2f(bf16 v){ return __bfloat162float(v); }
__device__ __forceinline__ bf16  f2b(float v){ return __float2bfloat16(v); }
__device__ __forceinline__ short f2s(float v){
  bf16 b = __float2bfloat16(v);
  short s; __builtin_memcpy(&s, &b, 2); return s;
}
__device__ __forceinline__ float s2f(short v){
  bf16 b; __builtin_memcpy(&b, &v, 2); return __bfloat162float(b);
}

// ---------- h0b[n][d] = bf16( sum_c atom_emb[c][x[n][c]][d] ) ----------
__global__ void k_h0(const int* __restrict__ x, const float* __restrict__ aemb,
                     bf16* __restrict__ h0b){
  int idx = blockIdx.x * 256 + threadIdx.x;
  if (idx >= NN * 64) return;
  int n = idx >> 6, d = idx & 63;
  float acc = 0.f;
  #pragma unroll
  for (int c = 0; c < 9; ++c){
    int a = x[n * 9 + c];
    acc += aemb[(c * 64 + a) * 64 + d];
  }
  h0b[idx] = f2b(acc);
}

// ---------- degree histogram + bond code ----------
__global__ void k_deg_code(const int* __restrict__ ei, const int* __restrict__ ea,
                           int* __restrict__ deg, int* __restrict__ code){
  int e = blockIdx.x * 256 + threadIdx.x;
  if (e >= NE) return;
  int dst = ei[NE + e];
  atomicAdd(&deg[dst], 1);
  code[e] = ea[e * 3] + 8 * ea[e * 3 + 1] + 64 * ea[e * 3 + 2];
}

// ---------- exclusive scan of deg -> rowptr ----------
__global__ void k_scan1(const int* __restrict__ deg, int* __restrict__ rowptr,
                        int* __restrict__ part){
  __shared__ int s[256];
  int t = threadIdx.x, i = blockIdx.x * 256 + t;
  int v = (i < NN) ? deg[i] : 0;
  s[t] = v; __syncthreads();
  for (int off = 1; off < 256; off <<= 1){
    int xv = (t >= off) ? s[t - off] : 0;
    __syncthreads();
    s[t] += xv;
    __syncthreads();
  }
  if (i < NN) rowptr[i] = s[t] - v;
  if (t == 255) part[blockIdx.x] = s[255];
}

__global__ void k_scan2(int* __restrict__ part, int nblk){
  __shared__ int s[256];
  int t = threadIdx.x;
  int v = (t < nblk) ? part[t] : 0;
  s[t] = v; __syncthreads();
  for (int off = 1; off < 256; off <<= 1){
    int xv = (t >= off) ? s[t - off] : 0;
    __syncthreads();
    s[t] += xv;
    __syncthreads();
  }
  if (t < nblk) part[t] = s[t] - v;
}

__global__ void k_scan3(int* __restrict__ rowptr, const int* __restrict__ part,
                        const int* __restrict__ deg, float* __restrict__ amp,
                        float* __restrict__ att){
  int i = blockIdx.x * 256 + threadIdx.x;
  if (i < NN){
    rowptr[i] += part[blockIdx.x];
    int d = deg[i];
    float ld = logf((float)max(d, 1) + 1.0f);
    amp[i] = ld / AVG_LOG_F;
    att[i] = AVG_LOG_F / ld;
  }
  if (i == 0) rowptr[NN] = NE;
}

// ---------- scatter edges into CSR order, packed (src, code) ----------
__global__ void k_scatter(const int* __restrict__ ei, const int* __restrict__ code,
                          const int* __restrict__ rowptr, int* __restrict__ cursor,
                          int2* __restrict__ sedge){
  int e = blockIdx.x * 256 + threadIdx.x;
  if (e >= NE) return;
  int dst = ei[NE + e];
  int pos = rowptr[dst] + atomicAdd(&cursor[dst], 1);
  int2 v; v.x = ei[e]; v.y = code[e];
  sedge[pos] = v;
}

// ---------- packed C table: CTp[(code*64+d)*8 + l] ----------
__global__ void k_ctab(const float* __restrict__ bemb, const float* __restrict__ preW,
                       bf16* __restrict__ CTp){
  __shared__ float et[64];
  int cb = blockIdx.x, l = blockIdx.y, t = threadIdx.x;
  int a0 = cb & 7, a1 = (cb >> 3) & 7, a2 = (cb >> 6) & 7;
  et[t] = bemb[(0 * 8 + a0) * 64 + t] + bemb[(1 * 8 + a1) * 64 + t] + bemb[(2 * 8 + a2) * 64 + t];
  __syncthreads();
  float acc = 0.f;
  const float* W = preW + (l * 192 + 128) * 64;
  for (int k = 0; k < 64; ++k) acc += et[k] * W[k * 64 + t];
  CTp[((size_t)cb * 64 + t) * 8 + l] = f2b(acc);
}

// ---------- Whsum / bias sums ----------
__global__ void k_whsum(const float* __restrict__ postW, const float* __restrict__ postb,
                        float* __restrict__ whs, float* __restrict__ bs){
  int idx = blockIdx.x * 256 + threadIdx.x;
  if (idx < 4096){
    int k = idx >> 6, d = idx & 63;
    float a = 0.f;
    for (int l = 0; l < 5; ++l) a += postW[(size_t)(l * 832 + 768 + k) * 64 + d];
    whs[idx] = a;
  }
  if (idx < 64){
    float a = 0.f;
    for (int l = 0; l < 5; ++l) a += postb[l * 64 + idx];
    bs[idx] = a;
  }
}

// ---------- Wt[l][cc][k] = postW[l][g*256 + k][c], cc=g*64+c ----------
__global__ void k_wt(const float* __restrict__ postW, bf16* __restrict__ Wt){
  int idx = blockIdx.x * 256 + threadIdx.x;
  if (idx >= 5 * 192 * 256) return;
  int l = idx / (192 * 256);
  int rem = idx % (192 * 256);
  int cc = rem >> 8;
  int k  = rem & 255;
  int g = cc >> 6, c = cc & 63;
  Wt[idx] = f2b(postW[((size_t)l * 832 + g * 256 + k) * 64 + c]);
}

// ---------- Wtp896[gc][k] + bias896 ----------
// gc<320: A-part Wdst_l col c (bias preb); 320..831: B-part packed d*8+l (Wsrc, pad 0);
// 832..895: h_lin fold: whs[k][c] + I (bias bsum)
__global__ void k_wtpre896(const float* __restrict__ preW, const float* __restrict__ preb,
                           const float* __restrict__ whs, const float* __restrict__ bs,
                           bf16* __restrict__ Wtp, float* __restrict__ bias896){
  int idx = blockIdx.x * 256 + threadIdx.x;
  if (idx < 896 * 64){
    int gc = idx >> 6, k = idx & 63;
    float v;
    if (gc < 320){
      int l = gc >> 6, c = gc & 63;
      v = preW[(size_t)(l * 192 + k) * 64 + c];
    } else if (gc < 832){
      int q = gc - 320, d = q >> 3, l = q & 7;
      v = (l < 5) ? preW[(size_t)(l * 192 + 64 + k) * 64 + d] : 0.f;
    } else {
      int c = gc - 832;
      v = whs[k * 64 + c] + ((k == c) ? 1.f : 0.f);
    }
    Wtp[idx] = f2b(v);
  }
  if (idx < 896){
    float b;
    if (idx < 320)      b = preb[(idx >> 6) * 64 + (idx & 63)];
    else if (idx < 832) b = 0.f;
    else                b = bs[idx - 832];
    bias896[idx] = b;
  }
}

// ---------- ABU+out = h0b[N,64] @ Wtp896[64,896] via MFMA ----------
// grid (391, 7): 128 rows x 128 cols/block; cols>=832 -> f32 out (h_lin base)
__global__ __launch_bounds__(256) void k_ab_mfma(const bf16* __restrict__ h0b,
                                                 const bf16* __restrict__ Wtp,
                                                 const float* __restrict__ bias896,
                                                 bf16* __restrict__ ABU,
                                                 float* __restrict__ out){
  __shared__ bf16 As[128][72];
  __shared__ bf16 Bs[128][72];
  const int t = threadIdx.x;
  const int n0 = blockIdx.x * 128;
  const int gc0 = blockIdx.y * 128;
  const int lane = t & 63, wid = t >> 6;
  const int rw = wid * 32;
  const short* H  = (const short*)h0b;
  const short* Wp = (const short*)Wtp;

  #pragma unroll
  for (int i = 0; i < 4; ++i){
    int idx = t + i * 256;
    int r = idx >> 3, ko = (idx & 7) * 8;
    int n = n0 + r;
    short8v v = short8v{0,0,0,0,0,0,0,0};
    if (n < NN) v = *(const short8v*)(H + (size_t)n * 64 + ko);
    *(short8v*)&As[r][ko] = v;
  }
  #pragma unroll
  for (int i = 0; i < 4; ++i){
    int idx = t + i * 256;
    int cc = idx >> 3, ko = (idx & 7) * 8;
    *(short8v*)&Bs[cc][ko] = *(const short8v*)(Wp + (size_t)(gc0 + cc) * 64 + ko);
  }
  __syncthreads();

  f32x4 acc[2][8] = {};
  #pragma unroll
  for (int kk = 0; kk < 2; ++kk){
    short8v af0 = *(const short8v*)&As[rw + (lane & 15)][kk * 32 + (lane >> 4) * 8];
    short8v af1 = *(const short8v*)&As[rw + 16 + (lane & 15)][kk * 32 + (lane >> 4) * 8];
    #pragma unroll
    for (int j = 0; j < 8; ++j){
      short8v bfj = *(const short8v*)&Bs[j * 16 + (lane & 15)][kk * 32 + (lane >> 4) * 8];
      acc[0][j] = __builtin_amdgcn_mfma_f32_16x16x32_bf16(af0, bfj, acc[0][j], 0, 0, 0);
      acc[1][j] = __builtin_amdgcn_mfma_f32_16x16x32_bf16(af1, bfj, acc[1][j], 0, 0, 0);
    }
  }

  #pragma unroll
  for (int i = 0; i < 2; ++i){
    #pragma unroll
    for (int r = 0; r < 4; ++r){
      int n = n0 + rw + i * 16 + (lane >> 4) * 4 + r;
      if (n >= NN) continue;
      #pragma unroll
      for (int j = 0; j < 8; ++j){
        int gc = gc0 + j * 16 + (lane & 15);
        float v = acc[i][j][r] + bias896[gc];
        if (gc < 832) ABU[(size_t)n * 832 + gc] = f2b(v);
        else          out[(size_t)n * 64 + (gc - 832)] = v;
      }
    }
  }
}

// ---------- fused aggregate + posttrans ----------
// 512 thr (8 waves), 16 nodes/block; gather: wave w -> nodes {w*2, w*2+1}, batch-4 MLP
// MFMA: waves 0-3 layers 0-2, waves 4-7 layers 3-4; cols (wid&3)*16 trio; LDS combine
__global__ __launch_bounds__(512, 6) void k_fused(const bf16* __restrict__ ABU,
                                                  const bf16* __restrict__ CTp,
                                                  const bf16* __restrict__ Wt,
                                                  const int* __restrict__ rowptr,
                                                  const int2* __restrict__ sedge,
                                                  const float* __restrict__ amp,
                                                  const float* __restrict__ att,
                                                  float* __restrict__ out){
  __shared__ __align__(16) short ag[5][16][264];
  const int t = threadIdx.x, lane = t & 63, wid = t >> 6;
  const int n0 = blockIdx.x * 16;
  const short* ABUs = (const short*)ABU;
  const short* CTps = (const short*)CTp;

  // ---- gather phase: 2 nodes/wave, 5 layers per edge, batch-4 loads ----
  #pragma unroll
  for (int i = 0; i < 2; ++i){
    int row = wid * 2 + i;
    int n = n0 + row;                       // NN % 16 == 0
    int r0 = rowptr[n], r1 = rowptr[n + 1];
    float s[5]  = {0.f, 0.f, 0.f, 0.f, 0.f};
    float sq[5] = {0.f, 0.f, 0.f, 0.f, 0.f};
    float mx[5], mn[5];
    #pragma unroll
    for (int l = 0; l < 5; ++l){ mx[l] = -1e30f; mn[l] = 1e30f; }

    for (int j = r0; j < r1; j += 4){
      int rem = r1 - j;
      int2 e[4];
      short8v av[4], cv[4];
      #pragma unroll
      for (int q = 0; q < 4; ++q)
        if (q < rem) e[q] = sedge[j + q];
      #pragma unroll
      for (int q = 0; q < 4; ++q)
        if (q < rem){
          av[q] = *(const short8v*)(ABUs + (size_t)e[q].x * 832 + 320 + lane * 8);
          cv[q] = *(const short8v*)(CTps + (size_t)e[q].y * 512 + lane * 8);
        }
      #pragma unroll
      for (int q = 0; q < 4; ++q)
        if (q < rem){
          #pragma unroll
          for (int l = 0; l < 5; ++l){
            float tv = s2f(av[q][l]) + s2f(cv[q][l]);
            s[l] += tv; sq[l] = fmaf(tv, tv, sq[l]);
            mx[l] = fmaxf(mx[l], tv); mn[l] = fminf(mn[l], tv);
          }
        }
    }
    int d = r1 - r0;
    float degc = (float)((d > 0) ? d : 1);
    #pragma unroll
    for (int l = 0; l < 5; ++l){
      float K = s2f(ABUs[(size_t)n * 832 + l * 64 + lane]);   // includes pre_b
      float mean = ((float)d * K + s[l]) / degc;
      float MX = (d > 0) ? (K + mx[l]) : 0.f;
      float MN = (d > 0) ? (K + mn[l]) : 0.f;
      float mu = s[l] / degc;
      float var = fmaxf(sq[l] / degc - mu * mu, 0.f);
      float sd = sqrtf(var + EPSV);
      ag[l][row][lane]       = f2s(mean);
      ag[l][row][64 + lane]  = f2s(MX);
      ag[l][row][128 + lane] = f2s(MN);
      ag[l][row][192 + lane] = f2s(sd);
    }
  }
  __syncthreads();

  // ---- MFMA phase: wave-halves split the layer loop ----
  const int w4 = wid & 3;
  const int lsta = (wid < 4) ? 0 : 3;
  const int lcnt = (wid < 4) ? 3 : 2;
  f32x4 acc[3] = {};
  const short* Wts = (const short*)Wt;
  for (int li = 0; li < lcnt; ++li){
    int l = lsta + li;
    const short* Wl = Wts + (size_t)l * 192 * 256;
    #pragma unroll
    for (int kt = 0; kt < 8; ++kt){
      short8v af = *(const short8v*)&ag[l][lane & 15][kt * 32 + (lane >> 4) * 8];
      #pragma unroll
      for (int g = 0; g < 3; ++g){
        const short* bp = Wl + (size_t)(g * 64 + w4 * 16 + (lane & 15)) * 256 +
                          kt * 32 + (lane >> 4) * 8;
        short8v bfv = *(const short8v*)bp;
        acc[g] = __builtin_amdgcn_mfma_f32_16x16x32_bf16(af, bfv, acc[g], 0, 0, 0);
      }
    }
  }
  __syncthreads();

  // ---- combine wave-halves via LDS overlay on ag ----
  f32x4* red = (f32x4*)&ag[0][0][0];
  if (wid >= 4){
    #pragma unroll
    for (int g = 0; g < 3; ++g)
      red[((wid - 4) * 3 + g) * 64 + lane] = acc[g];
  }
  __syncthreads();
  if (wid < 4){
    #pragma unroll
    for (int g = 0; g < 3; ++g){
      f32x4 o = red[(wid * 3 + g) * 64 + lane];
      acc[g][0] += o[0]; acc[g][1] += o[1]; acc[g][2] += o[2]; acc[g][3] += o[3];
    }
    // ---- epilogue: out += U + amp*V + att*W ----
    #pragma unroll
    for (int r = 0; r < 4; ++r){
      int row = (lane >> 4) * 4 + r;
      int n = n0 + row;
      float am = amp[n], at = att[n];
      int c = wid * 16 + (lane & 15);
      out[(size_t)n * 64 + c] += acc[0][r] + am * acc[1][r] + at * acc[2][r];
    }
  }
}

extern "C" void kernel_launch(void* const* d_in, const int* in_sizes, int n_in,
                              void* d_out, int out_size, void* d_ws, size_t ws_size,
                              hipStream_t stream){
  const int*   x     = (const int*)d_in[0];
  const int*   ei    = (const int*)d_in[1];
  const int*   ea    = (const int*)d_in[2];
  const float* aemb  = (const float*)d_in[3];
  const float* bemb  = (const float*)d_in[4];
  const float* preW  = (const float*)d_in[5];
  const float* preb  = (const float*)d_in[6];
  const float* postW = (const float*)d_in[7];
  const float* postb = (const float*)d_in[8];
  float* out = (float*)d_out;

  char* p = (char*)d_ws;
  auto alloc = [&](size_t bytes) -> char* {
    char* r = p;
    p += (bytes + 255) & ~(size_t)255;
    return r;
  };
  bf16*  h0b     = (bf16*) alloc((size_t)NN * 64 * 2);
  bf16*  ABU     = (bf16*) alloc((size_t)NN * 832 * 2);
  int*   deg     = (int*)  alloc((size_t)NN * 4);
  int*   rowptr  = (int*)  alloc((size_t)(NN + 1) * 4);
  int*   cursor  = (int*)  alloc((size_t)NN * 4);
  float* amp     = (float*)alloc((size_t)NN * 4);
  float* att     = (float*)alloc((size_t)NN * 4);
  int*   code    = (int*)  alloc((size_t)NE * 4);
  int2*  sedge   = (int2*) alloc((size_t)NE * 8);
  bf16*  CTp     = (bf16*) alloc((size_t)512 * 64 * 8 * 2);
  float* whs     = (float*)alloc((size_t)64 * 64 * 4);
  float* bs      = (float*)alloc((size_t)64 * 4);
  int*   part    = (int*)  alloc((size_t)256 * 4);
  bf16*  Wt      = (bf16*) alloc((size_t)5 * 192 * 256 * 2);
  bf16*  Wtp     = (bf16*) alloc((size_t)896 * 64 * 2);
  float* bias896 = (float*)alloc((size_t)896 * 4);
  if ((size_t)(p - (char*)d_ws) > ws_size) return;

  hipMemsetAsync(deg, 0, (size_t)NN * 4, stream);
  hipMemsetAsync(cursor, 0, (size_t)NN * 4, stream);

  k_h0<<<dim3((NN * 64 + 255) / 256), 256, 0, stream>>>(x, aemb, h0b);
  k_deg_code<<<dim3((NE + 255) / 256), 256, 0, stream>>>(ei, ea, deg, code);
  int nblk = (NN + 255) / 256;
  k_scan1<<<dim3(nblk), 256, 0, stream>>>(deg, rowptr, part);
  k_scan2<<<dim3(1), 256, 0, stream>>>(part, nblk);
  k_scan3<<<dim3(nblk), 256, 0, stream>>>(rowptr, part, deg, amp, att);
  k_scatter<<<dim3((NE + 255) / 256), 256, 0, stream>>>(ei, code, rowptr, cursor, sedge);
  k_ctab<<<dim3(512, 5), 64, 0, stream>>>(bemb, preW, CTp);
  k_whsum<<<dim3(16), 256, 0, stream>>>(postW, postb, whs, bs);
  k_wt<<<dim3((5 * 192 * 256 + 255) / 256), 256, 0, stream>>>(postW, Wt);
  k_wtpre896<<<dim3((896 * 64 + 255) / 256), 256, 0, stream>>>(preW, preb, whs, bs,
                                                               Wtp, bias896);
  k_ab_mfma<<<dim3((NN + 127) / 128, 7), 256, 0, stream>>>(h0b, Wtp, bias896, ABU, out);
  k_fused<<<dim3(NN / 16), 512, 0, stream>>>(ABU, CTp, Wt, rowptr, sedge,
                                             amp, att, out);
}

// Round 7
// 288.212 us; speedup vs baseline: 1.3630x; 1.3630x over previous
//
#include <hip/hip_runtime.h>
#include <hip/hip_bf16.h>

#define NN 50000
#define NE 400000
#define AVG_LOG_F 2.1972245773362196f
#define EPSV 1e-5f

typedef __hip_bfloat16 bf16;
typedef __attribute__((ext_vector_type(8))) short short8v;
typedef __attribute__((ext_vector_type(4))) float f32x4;

__device__ __forceinline__ float b2f(bf16 v){ return __bfloat162float(v); }
__device__ __forceinline__ bf16  f2b(float v){ return __float2bfloat16(v); }
__device__ __forceinline__ short f2s(float v){
  bf16 b = __float2bfloat16(v);
  short s; __builtin_memcpy(&s, &b, 2); return s;
}
__device__ __forceinline__ float s2f(short v){
  bf16 b; __builtin_memcpy(&b, &v, 2); return __bfloat162float(b);
}

// ---------- h0b[n][d] = bf16( sum_c atom_emb[c][x[n][c]][d] ) ----------
__global__ void k_h0(const int* __restrict__ x, const float* __restrict__ aemb,
                     bf16* __restrict__ h0b){
  int idx = blockIdx.x * 256 + threadIdx.x;
  if (idx >= NN * 64) return;
  int n = idx >> 6, d = idx & 63;
  float acc = 0.f;
  #pragma unroll
  for (int c = 0; c < 9; ++c){
    int a = x[n * 9 + c];
    acc += aemb[(c * 64 + a) * 64 + d];
  }
  h0b[idx] = f2b(acc);
}

// ---------- degree histogram + bond code ----------
__global__ void k_deg_code(const int* __restrict__ ei, const int* __restrict__ ea,
                           int* __restrict__ deg, int* __restrict__ code){
  int e = blockIdx.x * 256 + threadIdx.x;
  if (e >= NE) return;
  int dst = ei[NE + e];
  atomicAdd(&deg[dst], 1);
  code[e] = ea[e * 3] + 8 * ea[e * 3 + 1] + 64 * ea[e * 3 + 2];
}

// ---------- exclusive scan of deg -> rowptr ----------
__global__ void k_scan1(const int* __restrict__ deg, int* __restrict__ rowptr,
                        int* __restrict__ part){
  __shared__ int s[256];
  int t = threadIdx.x, i = blockIdx.x * 256 + t;
  int v = (i < NN) ? deg[i] : 0;
  s[t] = v; __syncthreads();
  for (int off = 1; off < 256; off <<= 1){
    int xv = (t >= off) ? s[t - off] : 0;
    __syncthreads();
    s[t] += xv;
    __syncthreads();
  }
  if (i < NN) rowptr[i] = s[t] - v;
  if (t == 255) part[blockIdx.x] = s[255];
}

__global__ void k_scan2(int* __restrict__ part, int nblk){
  __shared__ int s[256];
  int t = threadIdx.x;
  int v = (t < nblk) ? part[t] : 0;
  s[t] = v; __syncthreads();
  for (int off = 1; off < 256; off <<= 1){
    int xv = (t >= off) ? s[t - off] : 0;
    __syncthreads();
    s[t] += xv;
    __syncthreads();
  }
  if (t < nblk) part[t] = s[t] - v;
}

__global__ void k_scan3(int* __restrict__ rowptr, const int* __restrict__ part,
                        const int* __restrict__ deg, float* __restrict__ amp,
                        float* __restrict__ att){
  int i = blockIdx.x * 256 + threadIdx.x;
  if (i < NN){
    rowptr[i] += part[blockIdx.x];
    int d = deg[i];
    float ld = logf((float)max(d, 1) + 1.0f);
    amp[i] = ld / AVG_LOG_F;
    att[i] = AVG_LOG_F / ld;
  }
  if (i == 0) rowptr[NN] = NE;
}

// ---------- scatter edges into CSR order, packed (src, code) ----------
__global__ void k_scatter(const int* __restrict__ ei, const int* __restrict__ code,
                          const int* __restrict__ rowptr, int* __restrict__ cursor,
                          int2* __restrict__ sedge){
  int e = blockIdx.x * 256 + threadIdx.x;
  if (e >= NE) return;
  int dst = ei[NE + e];
  int pos = rowptr[dst] + atomicAdd(&cursor[dst], 1);
  int2 v; v.x = ei[e]; v.y = code[e];
  sedge[pos] = v;
}

// ---------- packed C table: CTp[(code*64+d)*8 + l] ----------
__global__ void k_ctab(const float* __restrict__ bemb, const float* __restrict__ preW,
                       bf16* __restrict__ CTp){
  __shared__ float et[64];
  int cb = blockIdx.x, l = blockIdx.y, t = threadIdx.x;
  int a0 = cb & 7, a1 = (cb >> 3) & 7, a2 = (cb >> 6) & 7;
  et[t] = bemb[(0 * 8 + a0) * 64 + t] + bemb[(1 * 8 + a1) * 64 + t] + bemb[(2 * 8 + a2) * 64 + t];
  __syncthreads();
  float acc = 0.f;
  const float* W = preW + (l * 192 + 128) * 64;
  for (int k = 0; k < 64; ++k) acc += et[k] * W[k * 64 + t];
  CTp[((size_t)cb * 64 + t) * 8 + l] = f2b(acc);
}

// ---------- Whsum / bias sums ----------
__global__ void k_whsum(const float* __restrict__ postW, const float* __restrict__ postb,
                        float* __restrict__ whs, float* __restrict__ bs){
  int idx = blockIdx.x * 256 + threadIdx.x;
  if (idx < 4096){
    int k = idx >> 6, d = idx & 63;
    float a = 0.f;
    for (int l = 0; l < 5; ++l) a += postW[(size_t)(l * 832 + 768 + k) * 64 + d];
    whs[idx] = a;
  }
  if (idx < 64){
    float a = 0.f;
    for (int l = 0; l < 5; ++l) a += postb[l * 64 + idx];
    bs[idx] = a;
  }
}

// ---------- WtK[g][c][l*256+k] = postW[l][g*256+k][c] (fragment-ready, K=1280) ----------
__global__ void k_wtk(const float* __restrict__ postW, bf16* __restrict__ WtK){
  int idx = blockIdx.x * 256 + threadIdx.x;
  if (idx >= 3 * 64 * 1280) return;
  int g = idx / (64 * 1280);
  int rem = idx % (64 * 1280);
  int c = rem / 1280;
  int kk = rem % 1280;
  int l = kk >> 8, k = kk & 255;
  WtK[idx] = f2b(postW[((size_t)l * 832 + g * 256 + k) * 64 + c]);
}

// ---------- Wtp896[gc][k] + bias896 ----------
// gc<320: A-part Wdst_l col c (bias preb); 320..831: B-part packed d*8+l (Wsrc, pad 0);
// 832..895: h_lin fold: whs[k][c] + I (bias bsum)
__global__ void k_wtpre896(const float* __restrict__ preW, const float* __restrict__ preb,
                           const float* __restrict__ whs, const float* __restrict__ bs,
                           bf16* __restrict__ Wtp, float* __restrict__ bias896){
  int idx = blockIdx.x * 256 + threadIdx.x;
  if (idx < 896 * 64){
    int gc = idx >> 6, k = idx & 63;
    float v;
    if (gc < 320){
      int l = gc >> 6, c = gc & 63;
      v = preW[(size_t)(l * 192 + k) * 64 + c];
    } else if (gc < 832){
      int q = gc - 320, d = q >> 3, l = q & 7;
      v = (l < 5) ? preW[(size_t)(l * 192 + 64 + k) * 64 + d] : 0.f;
    } else {
      int c = gc - 832;
      v = whs[k * 64 + c] + ((k == c) ? 1.f : 0.f);
    }
    Wtp[idx] = f2b(v);
  }
  if (idx < 896){
    float b;
    if (idx < 320)      b = preb[(idx >> 6) * 64 + (idx & 63)];
    else if (idx < 832) b = 0.f;
    else                b = bs[idx - 832];
    bias896[idx] = b;
  }
}

// ---------- ABU+out = h0b[N,64] @ Wtp896[64,896] via MFMA ----------
// grid (391, 7): 128 rows x 128 cols/block; cols>=832 -> f32 out (h_lin base)
__global__ __launch_bounds__(256) void k_ab_mfma(const bf16* __restrict__ h0b,
                                                 const bf16* __restrict__ Wtp,
                                                 const float* __restrict__ bias896,
                                                 bf16* __restrict__ ABU,
                                                 float* __restrict__ out){
  __shared__ bf16 As[128][72];
  __shared__ bf16 Bs[128][72];
  const int t = threadIdx.x;
  const int n0 = blockIdx.x * 128;
  const int gc0 = blockIdx.y * 128;
  const int lane = t & 63, wid = t >> 6;
  const int rw = wid * 32;
  const short* H  = (const short*)h0b;
  const short* Wp = (const short*)Wtp;

  #pragma unroll
  for (int i = 0; i < 4; ++i){
    int idx = t + i * 256;
    int r = idx >> 3, ko = (idx & 7) * 8;
    int n = n0 + r;
    short8v v = short8v{0,0,0,0,0,0,0,0};
    if (n < NN) v = *(const short8v*)(H + (size_t)n * 64 + ko);
    *(short8v*)&As[r][ko] = v;
  }
  #pragma unroll
  for (int i = 0; i < 4; ++i){
    int idx = t + i * 256;
    int cc = idx >> 3, ko = (idx & 7) * 8;
    *(short8v*)&Bs[cc][ko] = *(const short8v*)(Wp + (size_t)(gc0 + cc) * 64 + ko);
  }
  __syncthreads();

  f32x4 acc[2][8] = {};
  #pragma unroll
  for (int kk = 0; kk < 2; ++kk){
    short8v af0 = *(const short8v*)&As[rw + (lane & 15)][kk * 32 + (lane >> 4) * 8];
    short8v af1 = *(const short8v*)&As[rw + 16 + (lane & 15)][kk * 32 + (lane >> 4) * 8];
    #pragma unroll
    for (int j = 0; j < 8; ++j){
      short8v bfj = *(const short8v*)&Bs[j * 16 + (lane & 15)][kk * 32 + (lane >> 4) * 8];
      acc[0][j] = __builtin_amdgcn_mfma_f32_16x16x32_bf16(af0, bfj, acc[0][j], 0, 0, 0);
      acc[1][j] = __builtin_amdgcn_mfma_f32_16x16x32_bf16(af1, bfj, acc[1][j], 0, 0, 0);
    }
  }

  #pragma unroll
  for (int i = 0; i < 2; ++i){
    #pragma unroll
    for (int r = 0; r < 4; ++r){
      int n = n0 + rw + i * 16 + (lane >> 4) * 4 + r;
      if (n >= NN) continue;
      #pragma unroll
      for (int j = 0; j < 8; ++j){
        int gc = gc0 + j * 16 + (lane & 15);
        float v = acc[i][j][r] + bias896[gc];
        if (gc < 832) ABU[(size_t)n * 832 + gc] = f2b(v);
        else          out[(size_t)n * 64 + (gc - 832)] = v;
      }
    }
  }
}

// ---------- gather: one node per wave, all 5 layers, batch-4 explicit-scalar MLP ----------
// AGG[n][l*256 + a*64 + d], a in {mean,max,min,std}
__global__ __launch_bounds__(512) void k_gather(const bf16* __restrict__ ABU,
                                                const bf16* __restrict__ CTp,
                                                const int* __restrict__ rowptr,
                                                const int2* __restrict__ sedge,
                                                bf16* __restrict__ AGG){
  const int t = threadIdx.x, lane = t & 63, wid = t >> 6;
  const int n = blockIdx.x * 8 + wid;          // NN % 8 == 0, always valid
  const short* ABUs = (const short*)ABU;
  const short* CTps = (const short*)CTp;
  short* AGs = (short*)AGG;

  int r0 = rowptr[n], r1 = rowptr[n + 1];
  float s[5]  = {0.f, 0.f, 0.f, 0.f, 0.f};
  float sq[5] = {0.f, 0.f, 0.f, 0.f, 0.f};
  float mx[5], mn[5];
  #pragma unroll
  for (int l = 0; l < 5; ++l){ mx[l] = -1e30f; mn[l] = 1e30f; }

  for (int j = r0; j < r1; j += 4){
    int rem = r1 - j;
    int2 e0 = sedge[j];
    int2 e1 = (rem > 1) ? sedge[j + 1] : e0;
    int2 e2 = (rem > 2) ? sedge[j + 2] : e0;
    int2 e3 = (rem > 3) ? sedge[j + 3] : e0;
    // issue all payload loads (dup addresses on tail are harmless: accumulation guarded)
    short8v a0 = *(const short8v*)(ABUs + (size_t)e0.x * 832 + 320 + lane * 8);
    short8v c0 = *(const short8v*)(CTps + (size_t)e0.y * 512 + lane * 8);
    short8v a1 = *(const short8v*)(ABUs + (size_t)e1.x * 832 + 320 + lane * 8);
    short8v c1 = *(const short8v*)(CTps + (size_t)e1.y * 512 + lane * 8);
    short8v a2 = *(const short8v*)(ABUs + (size_t)e2.x * 832 + 320 + lane * 8);
    short8v c2 = *(const short8v*)(CTps + (size_t)e2.y * 512 + lane * 8);
    short8v a3 = *(const short8v*)(ABUs + (size_t)e3.x * 832 + 320 + lane * 8);
    short8v c3 = *(const short8v*)(CTps + (size_t)e3.y * 512 + lane * 8);

    #pragma unroll
    for (int l = 0; l < 5; ++l){
      float tv = s2f(a0[l]) + s2f(c0[l]);
      s[l] += tv; sq[l] = fmaf(tv, tv, sq[l]);
      mx[l] = fmaxf(mx[l], tv); mn[l] = fminf(mn[l], tv);
    }
    if (rem > 1){
      #pragma unroll
      for (int l = 0; l < 5; ++l){
        float tv = s2f(a1[l]) + s2f(c1[l]);
        s[l] += tv; sq[l] = fmaf(tv, tv, sq[l]);
        mx[l] = fmaxf(mx[l], tv); mn[l] = fminf(mn[l], tv);
      }
    }
    if (rem > 2){
      #pragma unroll
      for (int l = 0; l < 5; ++l){
        float tv = s2f(a2[l]) + s2f(c2[l]);
        s[l] += tv; sq[l] = fmaf(tv, tv, sq[l]);
        mx[l] = fmaxf(mx[l], tv); mn[l] = fminf(mn[l], tv);
      }
    }
    if (rem > 3){
      #pragma unroll
      for (int l = 0; l < 5; ++l){
        float tv = s2f(a3[l]) + s2f(c3[l]);
        s[l] += tv; sq[l] = fmaf(tv, tv, sq[l]);
        mx[l] = fmaxf(mx[l], tv); mn[l] = fminf(mn[l], tv);
      }
    }
  }

  int d = r1 - r0;
  float degc = (float)((d > 0) ? d : 1);
  size_t base = (size_t)n * 1280;
  #pragma unroll
  for (int l = 0; l < 5; ++l){
    float K = s2f(ABUs[(size_t)n * 832 + l * 64 + lane]);   // includes pre_b
    float mean = ((float)d * K + s[l]) / degc;
    float MX = (d > 0) ? (K + mx[l]) : 0.f;
    float MN = (d > 0) ? (K + mn[l]) : 0.f;
    float mu = s[l] / degc;
    float var = fmaxf(sq[l] / degc - mu * mu, 0.f);
    float sd = sqrtf(var + EPSV);
    AGs[base + l * 256 + lane]       = f2s(mean);
    AGs[base + l * 256 + 64 + lane]  = f2s(MX);
    AGs[base + l * 256 + 128 + lane] = f2s(MN);
    AGs[base + l * 256 + 192 + lane] = f2s(sd);
  }
}

// ---------- posttrans GEMM: out += AGG[N,1280] @ WtK[1280,192] with amp/att combine ----------
// grid 782, block 256 (4 waves); 64 rows/block; wave w owns col-triple {w*16, 64+w*16, 128+w*16}
__global__ __launch_bounds__(256) void k_post5(const bf16* __restrict__ AGG,
                                               const bf16* __restrict__ WtK,
                                               const float* __restrict__ amp,
                                               const float* __restrict__ att,
                                               float* __restrict__ out){
  __shared__ short As[64][136];   // 64 rows x BK=128 (+8 pad: 80B stride quantum -> 2-way max)
  const int t = threadIdx.x, lane = t & 63, wid = t >> 6;
  const int n0 = blockIdx.x * 64;
  const short* AGs = (const short*)AGG;
  const short* Ws  = (const short*)WtK;

  f32x4 acc[4][3] = {};
  for (int kt = 0; kt < 10; ++kt){
    __syncthreads();
    #pragma unroll
    for (int i = 0; i < 4; ++i){
      int id = t + i * 256;
      int r = id >> 4, ko = (id & 15) * 8;
      int n = n0 + r;
      short8v v = short8v{0,0,0,0,0,0,0,0};
      if (n < NN) v = *(const short8v*)(AGs + (size_t)n * 1280 + kt * 128 + ko);
      *(short8v*)&As[r][ko] = v;
    }
    __syncthreads();
    #pragma unroll
    for (int kk = 0; kk < 4; ++kk){
      short8v bfg[3];
      #pragma unroll
      for (int g = 0; g < 3; ++g)
        bfg[g] = *(const short8v*)(Ws + (size_t)(g * 64 + wid * 16 + (lane & 15)) * 1280 +
                                   kt * 128 + kk * 32 + (lane >> 4) * 8);
      #pragma unroll
      for (int rf = 0; rf < 4; ++rf){
        short8v af = *(const short8v*)&As[rf * 16 + (lane & 15)][kk * 32 + (lane >> 4) * 8];
        #pragma unroll
        for (int g = 0; g < 3; ++g)
          acc[rf][g] = __builtin_amdgcn_mfma_f32_16x16x32_bf16(af, bfg[g], acc[rf][g], 0, 0, 0);
      }
    }
  }

  #pragma unroll
  for (int rf = 0; rf < 4; ++rf){
    #pragma unroll
    for (int r = 0; r < 4; ++r){
      int n = n0 + rf * 16 + (lane >> 4) * 4 + r;
      if (n >= NN) continue;
      float am = amp[n], at = att[n];
      int c = wid * 16 + (lane & 15);
      out[(size_t)n * 64 + c] += acc[rf][0][r] + am * acc[rf][1][r] + at * acc[rf][2][r];
    }
  }
}

extern "C" void kernel_launch(void* const* d_in, const int* in_sizes, int n_in,
                              void* d_out, int out_size, void* d_ws, size_t ws_size,
                              hipStream_t stream){
  const int*   x     = (const int*)d_in[0];
  const int*   ei    = (const int*)d_in[1];
  const int*   ea    = (const int*)d_in[2];
  const float* aemb  = (const float*)d_in[3];
  const float* bemb  = (const float*)d_in[4];
  const float* preW  = (const float*)d_in[5];
  const float* preb  = (const float*)d_in[6];
  const float* postW = (const float*)d_in[7];
  const float* postb = (const float*)d_in[8];
  float* out = (float*)d_out;

  char* p = (char*)d_ws;
  auto alloc = [&](size_t bytes) -> char* {
    char* r = p;
    p += (bytes + 255) & ~(size_t)255;
    return r;
  };
  bf16*  h0b     = (bf16*) alloc((size_t)NN * 64 * 2);
  bf16*  ABU     = (bf16*) alloc((size_t)NN * 832 * 2);
  bf16*  AGG     = (bf16*) alloc((size_t)NN * 1280 * 2);
  int*   deg     = (int*)  alloc((size_t)NN * 4);
  int*   rowptr  = (int*)  alloc((size_t)(NN + 1) * 4);
  int*   cursor  = (int*)  alloc((size_t)NN * 4);
  float* amp     = (float*)alloc((size_t)NN * 4);
  float* att     = (float*)alloc((size_t)NN * 4);
  int*   code    = (int*)  alloc((size_t)NE * 4);
  int2*  sedge   = (int2*) alloc((size_t)NE * 8);
  bf16*  CTp     = (bf16*) alloc((size_t)512 * 64 * 8 * 2);
  float* whs     = (float*)alloc((size_t)64 * 64 * 4);
  float* bs      = (float*)alloc((size_t)64 * 4);
  int*   part    = (int*)  alloc((size_t)256 * 4);
  bf16*  WtK     = (bf16*) alloc((size_t)3 * 64 * 1280 * 2);
  bf16*  Wtp     = (bf16*) alloc((size_t)896 * 64 * 2);
  float* bias896 = (float*)alloc((size_t)896 * 4);
  if ((size_t)(p - (char*)d_ws) > ws_size) return;

  hipMemsetAsync(deg, 0, (size_t)NN * 4, stream);
  hipMemsetAsync(cursor, 0, (size_t)NN * 4, stream);

  k_h0<<<dim3((NN * 64 + 255) / 256), 256, 0, stream>>>(x, aemb, h0b);
  k_deg_code<<<dim3((NE + 255) / 256), 256, 0, stream>>>(ei, ea, deg, code);
  int nblk = (NN + 255) / 256;
  k_scan1<<<dim3(nblk), 256, 0, stream>>>(deg, rowptr, part);
  k_scan2<<<dim3(1), 256, 0, stream>>>(part, nblk);
  k_scan3<<<dim3(nblk), 256, 0, stream>>>(rowptr, part, deg, amp, att);
  k_scatter<<<dim3((NE + 255) / 256), 256, 0, stream>>>(ei, code, rowptr, cursor, sedge);
  k_ctab<<<dim3(512, 5), 64, 0, stream>>>(bemb, preW, CTp);
  k_whsum<<<dim3(16), 256, 0, stream>>>(postW, postb, whs, bs);
  k_wtk<<<dim3((3 * 64 * 1280 + 255) / 256), 256, 0, stream>>>(postW, WtK);
  k_wtpre896<<<dim3((896 * 64 + 255) / 256), 256, 0, stream>>>(preW, preb, whs, bs,
                                                               Wtp, bias896);
  k_ab_mfma<<<dim3((NN + 127) / 128, 7), 256, 0, stream>>>(h0b, Wtp, bias896, ABU, out);
  k_gather<<<dim3(NN / 8), 512, 0, stream>>>(ABU, CTp, rowptr, sedge, AGG);
  k_post5<<<dim3((NN + 63) / 64), 256, 0, stream>>>(AGG, WtK, amp, att, out);
}